// Round 1
// baseline (212.307 us; speedup 1.0000x reference)
//
#include <hip/hip_runtime.h>
#include <hip/hip_fp16.h>

#define N_TOT 65536
#define D_DIM 512
#define K_DIM 64
#define NC    32          // n-rows per LDS chunk (one MFMA K=32 step)
#define HT_S  40          // LDS row stride in bf16 elems = 80 B (16B-aligned rows)
#define GSZ   (K_DIM * D_DIM)   // 32768 elements of partial G

typedef __bf16   bf16x8 __attribute__((ext_vector_type(8)));
typedef float    f32x4  __attribute__((ext_vector_type(4)));
typedef float    f32x2  __attribute__((ext_vector_type(2)));
typedef _Float16 half8  __attribute__((ext_vector_type(8)));

__device__ __forceinline__ unsigned int pack_bf16(float a, float b) {
    union { float f; unsigned int u; } x, y;
    x.f = a; y.f = b;
    unsigned int lo = (x.u + 0x7fffu + ((x.u >> 16) & 1u)) >> 16;   // RNE
    unsigned int hi = (y.u + 0x7fffu + ((y.u >> 16) & 1u)) >> 16;
    return lo | (hi << 16);
}

// K1: per-block partial G = F_chunk^T * h_chunk (bf16 MFMA, fp32 acc -> fp16 store)
//     + per-block partial sum(h^2).
// Staging (v2): lane owns a d-QUAD; 4 x float4 global loads (16B/lane, 1KB per
//   wave-instruction, 4x fewer load instrs than the v1 scalar-dword path) ->
//   pack to bf16 -> 4 x ds_write_b64 into ht[d][n]. LDS write banking is ~2x on
//   half the banks but LDS has ~7x slack vs HBM time per chunk.
// Epilogue (v2): G tile repacked through LDS (reusing ht storage) and stored as
//   coalesced dwordx4 instead of 32 scalar 2B scattered stores per lane.
extern "C" __global__ void __launch_bounds__(1024)
k1_partial(const float* __restrict__ h, const float* __restrict__ F,
           float* __restrict__ trw_out, unsigned short* __restrict__ gpart,
           float* __restrict__ out, int rowsPerBlock) {
    __shared__ unsigned short ht[2][D_DIM * HT_S];   // 2 x 40960 B, ht[d][n]
    __shared__ unsigned short Ft[2][K_DIM * HT_S];   // 2 x  5120 B, Ft[k][n]
    __shared__ float red[16];

    const int tid = threadIdx.x;
    const int b   = blockIdx.x;
    if (b == 0 && tid == 0) out[0] = 0.0f;        // d_out is poisoned; zero before K2

    const int row0    = b * rowsPerBlock;
    const int nChunks = rowsPerBlock / NC;

    // staging ids (h): lane owns d-quad [4*sd, 4*sd+4); sg picks the 4-row n-group
    const int sd = tid & 127;     // d-quad
    const int sg = tid >> 7;      // 0..7 : n-group of 4
    // staging ids (F): threads 0..255 only; lane owns k-pair, fg picks 4-row group
    const int fk = (tid & 31) * 2;     // k-pair base
    const int fg = tid >> 5;           // 0..7 (valid for tid<256)
    // mfma ids
    const int wave = tid >> 6;    // 0..15 ; wave owns d in [32w, 32w+32)
    const int lane = tid & 63;
    const int m    = lane & 15;
    const int q    = lane >> 4;

    f32x4 acc[4][2];
    #pragma unroll
    for (int kt = 0; kt < 4; ++kt)
        #pragma unroll
        for (int dt = 0; dt < 2; ++dt)
            acc[kt][dt] = (f32x4){0.f, 0.f, 0.f, 0.f};

    float trw = 0.f;

    auto stage = [&](int c, int p) {
        const int r0 = row0 + c * NC;
        // h: 4 x float4 loads: rows r0+sg*4+j, cols 4sd..4sd+3
        const float* hb = h + (size_t)(r0 + sg * 4) * D_DIM + sd * 4;
        f32x4 v[4];
        #pragma unroll
        for (int j = 0; j < 4; ++j)
            v[j] = *(const f32x4*)(hb + (size_t)j * D_DIM);
        #pragma unroll
        for (int j = 0; j < 4; ++j)
            #pragma unroll
            for (int e = 0; e < 4; ++e)
                trw += v[j][e] * v[j][e];
        // pack per d-row: 4 n-values -> 8B ds_write_b64 at ht[d][sg*4]
        #pragma unroll
        for (int e = 0; e < 4; ++e) {
            uint2 pk;
            pk.x = pack_bf16(v[0][e], v[1][e]);
            pk.y = pack_bf16(v[2][e], v[3][e]);
            *(uint2*)&ht[p][(sd * 4 + e) * HT_S + sg * 4] = pk;
        }
        if (tid < 256) {
            // F: 4 x float2 loads: rows r0+fg*4+j, cols fk..fk+1
            const float* fb = F + (size_t)(r0 + fg * 4) * K_DIM + fk;
            f32x2 w[4];
            #pragma unroll
            for (int j = 0; j < 4; ++j)
                w[j] = *(const f32x2*)(fb + (size_t)j * K_DIM);
            #pragma unroll
            for (int e = 0; e < 2; ++e) {
                uint2 pk;
                pk.x = pack_bf16(w[0][e], w[1][e]);
                pk.y = pack_bf16(w[2][e], w[3][e]);
                *(uint2*)&Ft[p][(fk + e) * HT_S + fg * 4] = pk;
            }
        }
    };

    stage(0, 0);   // prologue

    for (int c = 0; c < nChunks; ++c) {
        __syncthreads();                          // buf[c&1] ready; other buf free
        if (c + 1 < nChunks) stage(c + 1, (c + 1) & 1);

        const int p = c & 1;
        bf16x8 bfrag[2], afrag[4];
        #pragma unroll
        for (int dt = 0; dt < 2; ++dt)
            bfrag[dt] = *(const bf16x8*)&ht[p][(wave * 32 + dt * 16 + m) * HT_S + q * 8];
        #pragma unroll
        for (int kt = 0; kt < 4; ++kt)
            afrag[kt] = *(const bf16x8*)&Ft[p][(kt * 16 + m) * HT_S + q * 8];
        #pragma unroll
        for (int kt = 0; kt < 4; ++kt)
            #pragma unroll
            for (int dt = 0; dt < 2; ++dt)
                acc[kt][dt] = __builtin_amdgcn_mfma_f32_16x16x32_bf16(
                    afrag[kt], bfrag[dt], acc[kt][dt], 0, 0, 0);
    }

    // ---- epilogue: repack G tile through LDS, store coalesced ----
    __syncthreads();                              // all frag reads done; ht free
    unsigned short* gt = &ht[0][0];               // 80 KB raw, need 64 KB
    #pragma unroll
    for (int kt = 0; kt < 4; ++kt)
        #pragma unroll
        for (int dt = 0; dt < 2; ++dt)
            #pragma unroll
            for (int r = 0; r < 4; ++r) {
                const int k = kt * 16 + q * 4 + r;      // C/D row = (lane>>4)*4 + reg
                const int d = wave * 32 + dt * 16 + m;  // C/D col = lane&15
                __half hv = __float2half(acc[kt][dt][r]);
                gt[k * D_DIM + d] = *(unsigned short*)&hv;
            }

    // tr_wtw partial: wave shuffle reduce (no LDS dependency)
    #pragma unroll
    for (int off = 32; off > 0; off >>= 1) trw += __shfl_down(trw, off, 64);
    if (lane == 0) red[wave] = trw;
    __syncthreads();                              // gt complete + red complete

    unsigned short* gp = gpart + (size_t)b * GSZ;
    #pragma unroll
    for (int it = 0; it < 4; ++it)                // 32768 u16 / 1024 thr = 4x 16B
        *(uint4*)(gp + it * 8192 + tid * 8) = *(const uint4*)(gt + it * 8192 + tid * 8);

    if (tid == 0) {
        float s = 0.f;
        #pragma unroll
        for (int w = 0; w < 16; ++w) s += red[w];
        trw_out[b] = s;
    }
}

// K2: out = sum_b trw[b] - sum_{k,d} (sum_b Gpart[b][k,d])^2
extern "C" __global__ void __launch_bounds__(512)
k2_reduce(const float* __restrict__ trw, const unsigned short* __restrict__ gpart,
          float* __restrict__ out, int P) {
    __shared__ float sh[32 * 16 * 8];   // 16 KB: [sub][oct][j]
    __shared__ float red2[8];

    const int tid = threadIdx.x;
    const int sub = tid >> 4;                  // 0..31 : b-split
    const int oct = tid & 15;
    const int tt  = blockIdx.x * 16 + oct;     // 0..4095 ; elements 8tt..8tt+7

    float g[8];
    #pragma unroll
    for (int j = 0; j < 8; ++j) g[j] = 0.f;

    const unsigned short* base = gpart + (size_t)tt * 8;
    for (int b = sub; b < P; b += 32) {
        half8 v = *(const half8*)(base + (size_t)b * GSZ);
        #pragma unroll
        for (int j = 0; j < 8; ++j) g[j] += (float)v[j];
    }
    #pragma unroll
    for (int j = 0; j < 8; ++j) sh[(sub * 16 + oct) * 8 + j] = g[j];
    __syncthreads();

    float val = 0.f;
    if (tid < 128) {
        const int o2 = tid >> 3, j = tid & 7;
        float s = 0.f;
        #pragma unroll
        for (int sb = 0; sb < 32; ++sb) s += sh[(sb * 16 + o2) * 8 + j];
        val = -s * s;
    } else if (blockIdx.x == 0 && tid - 128 < P) {
        val = trw[tid - 128];                  // fold tr_wtw partials in block 0
    }

    #pragma unroll
    for (int off = 32; off > 0; off >>= 1) val += __shfl_down(val, off, 64);
    if ((tid & 63) == 0) red2[tid >> 6] = val;
    __syncthreads();
    if (tid == 0) {
        float s = 0.f;
        #pragma unroll
        for (int w = 0; w < 8; ++w) s += red2[w];
        atomicAdd(out, s);
    }
}

extern "C" void kernel_launch(void* const* d_in, const int* in_sizes, int n_in,
                              void* d_out, int out_size, void* d_ws, size_t ws_size,
                              hipStream_t stream) {
    const float* h = (const float*)d_in[0];   // [65536, 512]
    const float* F = (const float*)d_in[1];   // [65536, 64]
    float* out = (float*)d_out;

    // ws layout: [0,4096): trw fp32 (P<=256) ; [4096, 4096+P*64KiB): fp16 partial G
    int P = 256;
    while (P > 1 && (size_t)4096 + (size_t)P * (GSZ * 2) > ws_size) P >>= 1;
    const int rowsPerBlock = N_TOT / P;

    float* trw = (float*)d_ws;
    unsigned short* gpart = (unsigned short*)((char*)d_ws + 4096);

    hipLaunchKernelGGL(k1_partial, dim3(P), dim3(1024), 0, stream,
                       h, F, trw, gpart, out, rowsPerBlock);
    hipLaunchKernelGGL(k2_reduce, dim3(256), dim3(512), 0, stream,
                       trw, gpart, out, P);
}